// Round 1
// baseline (213.481 us; speedup 1.0000x reference)
//
#include <hip/hip_runtime.h>

#define BIGV 1e4f

constexpr int TW = 128;   // tile width  (output px per block, x)
constexpr int TH = 16;    // tile height (output px per block, y)

__global__ __launch_bounds__(256) void opening_kernel(
    const float* __restrict__ img, const int* __restrict__ kern,
    float* __restrict__ out, int H, int W)
{
    // img tile + halo 2 (needed to produce eroded values at halo 1)
    __shared__ float s_img[TH + 4][TW + 4];
    // eroded tile + halo 1; OOB-of-image positions hold -BIG (dilation pad)
    __shared__ float s_ero[TH + 2][TW + 2];

    const int tid   = threadIdx.x;
    const int x0    = blockIdx.x * TW;
    const int y0    = blockIdx.y * TH;
    const size_t pbase = (size_t)blockIdx.z * H * W;

    // runtime structuring element: mask[k] = (kernel[k] == 1), k = di*3+dj
    bool m[9];
#pragma unroll
    for (int k = 0; k < 9; ++k) m[k] = (kern[k] == 1);

    // ---- stage 1: global -> LDS, img tile with halo 2 (OOB -> +BIG) ----
    for (int idx = tid; idx < (TH + 4) * (TW + 4); idx += 256) {
        int r  = idx / (TW + 4);
        int c  = idx % (TW + 4);
        int gy = y0 - 2 + r;
        int gx = x0 - 2 + c;
        float v = BIGV;                       // erosion pad value
        if (gy >= 0 && gy < H && gx >= 0 && gx < W)
            v = img[pbase + (size_t)gy * W + gx];
        s_img[r][c] = v;
    }
    __syncthreads();

    // ---- stage 2: erosion for tile + halo 1 ----
    // eroded(r,c) corresponds to global (y0-1+r, x0-1+c)
    for (int idx = tid; idx < (TH + 2) * (TW + 2); idx += 256) {
        int r  = idx / (TW + 2);
        int c  = idx % (TW + 2);
        int gy = y0 - 1 + r;
        int gx = x0 - 1 + c;
        float e = -BIGV;                      // dilation pad for OOB positions
        if (gy >= 0 && gy < H && gx >= 0 && gx < W) {
            e = BIGV;
#pragma unroll
            for (int k = 0; k < 9; ++k) {
                const int di = k / 3, dj = k % 3;
                float v = s_img[r + di][c + dj];   // s_img shifted by (-2,-2)
                e = fminf(e, m[k] ? v : BIGV);     // masked-out -> BIG
            }
        }
        s_ero[r][c] = e;
    }
    __syncthreads();

    // ---- stage 3: dilation of eroded tile, coalesced store ----
    for (int idx = tid; idx < TH * TW; idx += 256) {
        int r = idx >> 7;          // / TW (TW == 128)
        int c = idx & (TW - 1);    // % TW
        float d = -BIGV;
#pragma unroll
        for (int k = 0; k < 9; ++k) {
            const int di = k / 3, dj = k % 3;
            float v = s_ero[r + di][c + dj];       // s_ero shifted by (-1,-1)
            d = fmaxf(d, m[k] ? v : -BIGV);
        }
        int gy = y0 + r, gx = x0 + c;
        if (gy < H && gx < W)
            out[pbase + (size_t)gy * W + gx] = d;
    }
}

extern "C" void kernel_launch(void* const* d_in, const int* in_sizes, int n_in,
                              void* d_out, int out_size, void* d_ws, size_t ws_size,
                              hipStream_t stream) {
    const float* img  = (const float*)d_in[0];
    const int*   kern = (const int*)d_in[1];
    float*       out  = (float*)d_out;

    const int H = 1024, W = 1024;
    const int planes = in_sizes[0] / (H * W);   // B*C = 24

    dim3 block(256);
    dim3 grid((W + TW - 1) / TW, (H + TH - 1) / TH, planes);
    opening_kernel<<<grid, block, 0, stream>>>(img, kern, out, H, W);
}

// Round 2
// 183.409 us; speedup vs baseline: 1.1640x; 1.1640x over previous
//
#include <hip/hip_runtime.h>

#define BIGV 1e4f

constexpr int RH = 16;  // output rows per thread
constexpr int TY = 4;   // y-groups per block (one wave each); block covers TY*RH = 64 rows
// Each block: 256 threads = 4 waves; lanes 0..63 of each wave cover 64*4 = 256 px in x.

struct Row { float2 L; float4 M; float2 R; };   // img columns gx-2 .. gx+5
struct Ero { float eL; float4 eM; float eR; };  // eroded columns gx-1 .. gx+4

__device__ __forceinline__ float min3f(float a, float b, float c) { return fminf(fminf(a, b), c); }
__device__ __forceinline__ float max3f(float a, float b, float c) { return fmaxf(fmaxf(a, b), c); }

__device__ __forceinline__ Row load_row(const float* __restrict__ p,
                                        int y, int gx, int H, int W) {
    Row r;
    if (y >= 0 && y < H) {                     // wave-uniform branch (y uniform per wave)
        const float* q = p + (size_t)y * W;
        r.M = *(const float4*)(q + gx);
        if (gx > 0)      r.L = *(const float2*)(q + gx - 2);   // gx-2 is 8B-aligned
        else             r.L = make_float2(BIGV, BIGV);
        if (gx + 4 < W)  r.R = *(const float2*)(q + gx + 4);
        else             r.R = make_float2(BIGV, BIGV);
    } else {
        r.L = make_float2(BIGV, BIGV);
        r.M = make_float4(BIGV, BIGV, BIGV, BIGV);
        r.R = make_float2(BIGV, BIGV);
    }
    return r;
}

// compile-time indexed access (q in [-2,5]) — folds under full unroll
__device__ __forceinline__ float rget(const Row& r, int q) {
    switch (q) {
        case -2: return r.L.x; case -1: return r.L.y;
        case 0:  return r.M.x; case 1:  return r.M.y;
        case 2:  return r.M.z; case 3:  return r.M.w;
        case 4:  return r.R.x; default: return r.R.y;
    }
}
__device__ __forceinline__ float eget(const Ero& e, int q) {
    switch (q) {
        case -1: return e.eL;
        case 0:  return e.eM.x; case 1:  return e.eM.y;
        case 2:  return e.eM.z; case 3:  return e.eM.w;
        default: return e.eR;
    }
}

// ---- cross structuring element fast path: min/max over {C,N,S,W,E} ----
__device__ __forceinline__ Ero erode_cross(const Row& a, const Row& b, const Row& c,
                                           int r, int H, int gx, int W) {
    Ero e;
    if (r >= 0 && r < H) {
        float vL = min3f(a.L.y, b.L.y, c.L.y);
        float v0 = min3f(a.M.x, b.M.x, c.M.x);
        float v1 = min3f(a.M.y, b.M.y, c.M.y);
        float v2 = min3f(a.M.z, b.M.z, c.M.z);
        float v3 = min3f(a.M.w, b.M.w, c.M.w);
        float vR = min3f(a.R.x, b.R.x, c.R.x);
        e.eL   = min3f(vL, b.L.x, b.M.x);
        e.eM.x = min3f(v0, b.L.y, b.M.y);
        e.eM.y = min3f(v1, b.M.x, b.M.z);
        e.eM.z = min3f(v2, b.M.y, b.M.w);
        e.eM.w = min3f(v3, b.M.z, b.R.x);
        e.eR   = min3f(vR, b.M.w, b.R.y);
        if (gx == 0)     e.eL = -BIGV;   // eroded col -1 is the dilation pad
        if (gx + 4 >= W) e.eR = -BIGV;   // eroded col W  is the dilation pad
    } else {
        e.eL = -BIGV; e.eM = make_float4(-BIGV, -BIGV, -BIGV, -BIGV); e.eR = -BIGV;
    }
    return e;
}

__device__ __forceinline__ float4 dilate_cross(const Ero& t, const Ero& m, const Ero& b) {
    float vx = max3f(t.eM.x, m.eM.x, b.eM.x);
    float vy = max3f(t.eM.y, m.eM.y, b.eM.y);
    float vz = max3f(t.eM.z, m.eM.z, b.eM.z);
    float vw = max3f(t.eM.w, m.eM.w, b.eM.w);
    float4 o;
    o.x = max3f(vx, m.eL,   m.eM.y);
    o.y = max3f(vy, m.eM.x, m.eM.z);
    o.z = max3f(vz, m.eM.y, m.eM.w);
    o.w = max3f(vw, m.eM.z, m.eR);
    return o;
}

// ---- generic runtime-mask fallback (uniform branch; not taken in this bench) ----
__device__ __forceinline__ Ero erode_gen(const Row& a, const Row& b, const Row& c,
                                         const bool* m, int r, int H, int gx, int W) {
    Ero e;
    if (r >= 0 && r < H) {
        float v[6];
#pragma unroll
        for (int p = 0; p < 6; ++p) {        // eroded column gx-1+p
            float acc = BIGV;
#pragma unroll
            for (int k = 0; k < 9; ++k) {
                const int di = k / 3, dj = k % 3;
                const Row& rr = (di == 0) ? a : ((di == 1) ? b : c);
                float t = rget(rr, p - 2 + dj);
                acc = fminf(acc, m[k] ? t : BIGV);
            }
            v[p] = acc;
        }
        e.eL = v[0]; e.eM.x = v[1]; e.eM.y = v[2]; e.eM.z = v[3]; e.eM.w = v[4]; e.eR = v[5];
        if (gx == 0)     e.eL = -BIGV;
        if (gx + 4 >= W) e.eR = -BIGV;
    } else {
        e.eL = -BIGV; e.eM = make_float4(-BIGV, -BIGV, -BIGV, -BIGV); e.eR = -BIGV;
    }
    return e;
}

__device__ __forceinline__ float4 dilate_gen(const Ero& e0, const Ero& e1, const Ero& e2,
                                             const bool* m) {
    float o[4];
#pragma unroll
    for (int j = 0; j < 4; ++j) {
        float acc = -BIGV;
#pragma unroll
        for (int k = 0; k < 9; ++k) {
            const int di = k / 3, dj = k % 3;
            const Ero& ee = (di == 0) ? e0 : ((di == 1) ? e1 : e2);
            float t = eget(ee, j + dj - 1);
            acc = fmaxf(acc, m[k] ? t : -BIGV);
        }
        o[j] = acc;
    }
    return make_float4(o[0], o[1], o[2], o[3]);
}

template <bool CROSS>
__device__ __forceinline__ void run(const float* __restrict__ img, float* __restrict__ out,
                                    const bool* m, int gx, int y0, int H, int W) {
    // pipeline: to output row y need eroded rows y-1..y+1, which need img rows y-2..y+2
    Row B = load_row(img, y0 - 2, gx, H, W);
    Row C = load_row(img, y0 - 1, gx, H, W);
    Row D = load_row(img, y0,     gx, H, W);
    Ero E0 = CROSS ? erode_cross(B, C, D, y0 - 1, H, gx, W)
                   : erode_gen(B, C, D, m, y0 - 1, H, gx, W);
    C = D;                      // keep img rows y0-? : C = img[y0-0]... roll below
    // reload pattern: keep (C = img[y], D = img[y+1]) entering each iteration
    Row Cc = load_row(img, y0,     gx, H, W);  // img[y0]   (reuse of D above; kept explicit)
    Row Dd = load_row(img, y0 + 1, gx, H, W);  // img[y0+1]
    Ero E1 = CROSS ? erode_cross(load_row(img, y0 - 1, gx, H, W), Cc, Dd, y0, H, gx, W)
                   : erode_gen(load_row(img, y0 - 1, gx, H, W), Cc, Dd, m, y0, H, gx, W);
#pragma unroll
    for (int i = 0; i < RH; ++i) {
        const int y = y0 + i;
        Row N = load_row(img, y + 2, gx, H, W);
        Ero E2 = CROSS ? erode_cross(Cc, Dd, N, y + 1, H, gx, W)
                       : erode_gen(Cc, Dd, N, m, y + 1, H, gx, W);
        float4 o = CROSS ? dilate_cross(E0, E1, E2) : dilate_gen(E0, E1, E2, m);
        *(float4*)(out + (size_t)y * W + gx) = o;
        Cc = Dd; Dd = N;
        E0 = E1; E1 = E2;
    }
}

__global__ __launch_bounds__(256) void opening_kernel(
    const float* __restrict__ img, const int* __restrict__ kern,
    float* __restrict__ out, int H, int W)
{
    const int lx = threadIdx.x & 63;          // lane within wave -> x strip
    const int ty = threadIdx.x >> 6;          // wave index -> y group (wave-uniform)
    const int gx = blockIdx.x * 256 + lx * 4;
    const int y0 = (blockIdx.y * TY + ty) * RH;
    const size_t pbase = (size_t)blockIdx.z * H * W;

    bool m[9];
#pragma unroll
    for (int k = 0; k < 9; ++k) m[k] = (kern[k] == 1);

    const bool cross = m[1] && m[3] && m[4] && m[5] && m[7] &&
                       !m[0] && !m[2] && !m[6] && !m[8];

    if (cross) run<true >(img + pbase, out + pbase, m, gx, y0, H, W);
    else       run<false>(img + pbase, out + pbase, m, gx, y0, H, W);
}

extern "C" void kernel_launch(void* const* d_in, const int* in_sizes, int n_in,
                              void* d_out, int out_size, void* d_ws, size_t ws_size,
                              hipStream_t stream) {
    const float* img  = (const float*)d_in[0];
    const int*   kern = (const int*)d_in[1];
    float*       out  = (float*)d_out;

    const int H = 1024, W = 1024;
    const int planes = in_sizes[0] / (H * W);   // B*C = 24

    dim3 block(256);
    dim3 grid(W / 256, H / (TY * RH), planes);  // (4, 16, 24)
    opening_kernel<<<grid, block, 0, stream>>>(img, kern, out, H, W);
}

// Round 3
// 179.689 us; speedup vs baseline: 1.1881x; 1.0207x over previous
//
#include <hip/hip_runtime.h>

#define BIGV 1e4f

constexpr int RH = 8;   // output rows per thread
constexpr int TY = 4;   // waves per block (each wave = one y-group); block covers 32 rows

struct Raw { float4 M; float2 L; float2 R; };   // M: gx..gx+3 ; L/R only valid on edge lanes
struct Row { float2 L; float4 M; float2 R; };   // img columns gx-2 .. gx+5
struct Ero { float eL; float4 eM; float eR; };  // eroded columns gx-1 .. gx+4

__device__ __forceinline__ float min3f(float a, float b, float c) { return fminf(fminf(a, b), c); }
__device__ __forceinline__ float max3f(float a, float b, float c) { return fmaxf(fmaxf(a, b), c); }

// raw load: one float4 per lane; halo float2 only on the wave's edge lanes (exec-masked)
__device__ __forceinline__ Raw load_raw(const float* __restrict__ img, int y, int gx,
                                        int lx, int H, int W) {
    Raw r;
    r.L = make_float2(BIGV, BIGV);
    r.R = make_float2(BIGV, BIGV);
    if (y >= 0 && y < H) {                         // wave-uniform (y uniform per wave)
        const float* q = img + (size_t)y * W;
        r.M = *(const float4*)(q + gx);
        if (lx == 0  && gx > 0)     r.L = *(const float2*)(q + gx - 2);
        if (lx == 63 && gx + 4 < W) r.R = *(const float2*)(q + gx + 4);
    } else {
        r.M = make_float4(BIGV, BIGV, BIGV, BIGV);
    }
    return r;
}

// build full 8-wide row: interior halo from neighbor lanes via shuffle
__device__ __forceinline__ Row rowify(const Raw& r, int lx) {
    Row o;
    o.M = r.M;
    float lz = __shfl_up(r.M.z, 1, 64);    // lane-1's gx+2  -> my gx-2
    float lw = __shfl_up(r.M.w, 1, 64);    // lane-1's gx+3  -> my gx-1
    float rx = __shfl_down(r.M.x, 1, 64);  // lane+1's gx    -> my gx+4
    float ry = __shfl_down(r.M.y, 1, 64);  // lane+1's gx+1  -> my gx+5
    o.L = (lx == 0)  ? r.L : make_float2(lz, lw);
    o.R = (lx == 63) ? r.R : make_float2(rx, ry);
    return o;
}

// compile-time indexed access (folds under full unroll) — generic path only
__device__ __forceinline__ float rget(const Row& r, int q) {
    switch (q) {
        case -2: return r.L.x; case -1: return r.L.y;
        case 0:  return r.M.x; case 1:  return r.M.y;
        case 2:  return r.M.z; case 3:  return r.M.w;
        case 4:  return r.R.x; default: return r.R.y;
    }
}
__device__ __forceinline__ float eget(const Ero& e, int q) {
    switch (q) {
        case -1: return e.eL;
        case 0:  return e.eM.x; case 1:  return e.eM.y;
        case 2:  return e.eM.z; case 3:  return e.eM.w;
        default: return e.eR;
    }
}

// ---- cross structuring element fast path: min over {C,N,S,W,E} ----
__device__ __forceinline__ Ero erode_cross(const Row& a, const Row& b, const Row& c,
                                           int r, int H, int gx, int W) {
    Ero e;
    if (r >= 0 && r < H) {                         // wave-uniform
        e.eL   = min3f(min3f(a.L.y, b.L.y, c.L.y), b.L.x, b.M.x);
        e.eM.x = min3f(min3f(a.M.x, b.M.x, c.M.x), b.L.y, b.M.y);
        e.eM.y = min3f(min3f(a.M.y, b.M.y, c.M.y), b.M.x, b.M.z);
        e.eM.z = min3f(min3f(a.M.z, b.M.z, c.M.z), b.M.y, b.M.w);
        e.eM.w = min3f(min3f(a.M.w, b.M.w, c.M.w), b.M.z, b.R.x);
        e.eR   = min3f(min3f(a.R.x, b.R.x, c.R.x), b.M.w, b.R.y);
        if (gx == 0)     e.eL = -BIGV;   // eroded col -1 is the dilation pad
        if (gx + 4 >= W) e.eR = -BIGV;   // eroded col W  is the dilation pad
    } else {
        e.eL = -BIGV; e.eM = make_float4(-BIGV, -BIGV, -BIGV, -BIGV); e.eR = -BIGV;
    }
    return e;
}

__device__ __forceinline__ float4 dilate_cross(const Ero& t, const Ero& m, const Ero& b) {
    float4 o;
    o.x = max3f(max3f(t.eM.x, m.eM.x, b.eM.x), m.eL,   m.eM.y);
    o.y = max3f(max3f(t.eM.y, m.eM.y, b.eM.y), m.eM.x, m.eM.z);
    o.z = max3f(max3f(t.eM.z, m.eM.z, b.eM.z), m.eM.y, m.eM.w);
    o.w = max3f(max3f(t.eM.w, m.eM.w, b.eM.w), m.eM.z, m.eR);
    return o;
}

// ---- generic runtime-mask fallback (uniform branch; not taken in this bench) ----
__device__ __forceinline__ Ero erode_gen(const Row& a, const Row& b, const Row& c,
                                         const bool* m, int r, int H, int gx, int W) {
    Ero e;
    if (r >= 0 && r < H) {
        float v[6];
#pragma unroll
        for (int p = 0; p < 6; ++p) {              // eroded column gx-1+p
            float acc = BIGV;
#pragma unroll
            for (int k = 0; k < 9; ++k) {
                const int di = k / 3, dj = k % 3;
                const Row& rr = (di == 0) ? a : ((di == 1) ? b : c);
                float t = rget(rr, p - 2 + dj);
                acc = fminf(acc, m[k] ? t : BIGV);
            }
            v[p] = acc;
        }
        e.eL = v[0]; e.eM.x = v[1]; e.eM.y = v[2]; e.eM.z = v[3]; e.eM.w = v[4]; e.eR = v[5];
        if (gx == 0)     e.eL = -BIGV;
        if (gx + 4 >= W) e.eR = -BIGV;
    } else {
        e.eL = -BIGV; e.eM = make_float4(-BIGV, -BIGV, -BIGV, -BIGV); e.eR = -BIGV;
    }
    return e;
}

__device__ __forceinline__ float4 dilate_gen(const Ero& e0, const Ero& e1, const Ero& e2,
                                             const bool* m) {
    float o[4];
#pragma unroll
    for (int j = 0; j < 4; ++j) {
        float acc = -BIGV;
#pragma unroll
        for (int k = 0; k < 9; ++k) {
            const int di = k / 3, dj = k % 3;
            const Ero& ee = (di == 0) ? e0 : ((di == 1) ? e1 : e2);
            float t = eget(ee, j + dj - 1);
            acc = fmaxf(acc, m[k] ? t : -BIGV);
        }
        o[j] = acc;
    }
    return make_float4(o[0], o[1], o[2], o[3]);
}

template <bool CROSS>
__device__ __forceinline__ void run(const float* __restrict__ img, float* __restrict__ out,
                                    const bool* m, int gx, int y0, int lx, int H, int W) {
    // prologue: Rows y0-2..y0+1, Eros y0-1, y0
    Raw rb = load_raw(img, y0 - 2, gx, lx, H, W);
    Raw rc = load_raw(img, y0 - 1, gx, lx, H, W);
    Raw rd = load_raw(img, y0,     gx, lx, H, W);
    Raw re = load_raw(img, y0 + 1, gx, lx, H, W);
    Raw pref = load_raw(img, y0 + 2, gx, lx, H, W);   // prefetch for i=0

    Row B   = rowify(rb, lx);
    Row C   = rowify(rc, lx);
    Row Cur = rowify(rd, lx);   // Row(y0)
    Ero E0 = CROSS ? erode_cross(B, C, Cur, y0 - 1, H, gx, W)
                   : erode_gen(B, C, Cur, m, y0 - 1, H, gx, W);
    Row Nxt = rowify(re, lx);   // Row(y0+1)
    Ero E1 = CROSS ? erode_cross(C, Cur, Nxt, y0, H, gx, W)
                   : erode_gen(C, Cur, Nxt, m, y0, H, gx, W);

#pragma unroll
    for (int i = 0; i < RH; ++i) {
        const int y = y0 + i;
        Raw pref2 = pref;
        if (i < RH - 1)                               // compile-time under unroll
            pref2 = load_raw(img, y + 3, gx, lx, H, W);  // prefetch next iter's row
        Row N = rowify(pref, lx);                     // Row(y+2), loaded last iter
        Ero E2 = CROSS ? erode_cross(Cur, Nxt, N, y + 1, H, gx, W)
                       : erode_gen(Cur, Nxt, N, m, y + 1, H, gx, W);
        float4 o = CROSS ? dilate_cross(E0, E1, E2) : dilate_gen(E0, E1, E2, m);
        *(float4*)(out + (size_t)y * W + gx) = o;
        Cur = Nxt; Nxt = N;
        E0 = E1; E1 = E2;
        pref = pref2;
    }
}

__global__ __launch_bounds__(256) void opening_kernel(
    const float* __restrict__ img, const int* __restrict__ kern,
    float* __restrict__ out, int H, int W)
{
    const int lx = threadIdx.x & 63;          // lane -> x strip
    const int ty = threadIdx.x >> 6;          // wave -> y group (wave-uniform)
    const int gx = blockIdx.x * 256 + lx * 4;
    const int y0 = (blockIdx.y * TY + ty) * RH;
    const size_t pbase = (size_t)blockIdx.z * H * W;

    bool m[9];
#pragma unroll
    for (int k = 0; k < 9; ++k) m[k] = (kern[k] == 1);

    const bool cross = m[1] && m[3] && m[4] && m[5] && m[7] &&
                       !m[0] && !m[2] && !m[6] && !m[8];

    if (cross) run<true >(img + pbase, out + pbase, m, gx, y0, lx, H, W);
    else       run<false>(img + pbase, out + pbase, m, gx, y0, lx, H, W);
}

extern "C" void kernel_launch(void* const* d_in, const int* in_sizes, int n_in,
                              void* d_out, int out_size, void* d_ws, size_t ws_size,
                              hipStream_t stream) {
    const float* img  = (const float*)d_in[0];
    const int*   kern = (const int*)d_in[1];
    float*       out  = (float*)d_out;

    const int H = 1024, W = 1024;
    const int planes = in_sizes[0] / (H * W);   // B*C = 24

    dim3 block(256);
    dim3 grid(W / 256, H / (TY * RH), planes);  // (4, 32, 24) = 3072 blocks
    opening_kernel<<<grid, block, 0, stream>>>(img, kern, out, H, W);
}